// Round 12
// baseline (361.018 us; speedup 1.0000x reference)
//
#include <hip/hip_runtime.h>
#include <stdint.h>

#define B_ 4
#define T_ 64
#define P_ 256
#define E_ 512
#define H_ 8
#define D_ 64
#define NF 1536
#define MCH 16384   // tokens per b-chunk (T_*P_)

typedef unsigned short u16;
typedef __attribute__((ext_vector_type(8))) __bf16 bf16x8;
typedef __attribute__((ext_vector_type(4))) float f32x4;
typedef __attribute__((ext_vector_type(16))) float f32x16;

__device__ __forceinline__ u16 f2bf(float x) {
  union { float f; uint32_t u; } a; a.f = x;
  uint32_t u = a.u;
  uint32_t r = (u + 0x7FFFu + ((u >> 16) & 1u)) >> 16;
  return (u16)r;
}

__device__ __forceinline__ bf16x8 ld8(const u16* p) {
  union { uint4 u; bf16x8 b; } t;
  t.u = *reinterpret_cast<const uint4*>(p);
  return t.b;
}

typedef __attribute__((address_space(3))) void lds_void;
typedef __attribute__((address_space(1))) void g_void;
__device__ __forceinline__ void gl_lds16(const void* g, void* l) {
  __builtin_amdgcn_global_load_lds((g_void*)g, (lds_void*)l, 16, 0, 0);
}

__device__ __forceinline__ f32x4 mfma16(bf16x8 a, bf16x8 b, f32x4 c) {
  return __builtin_amdgcn_mfma_f32_16x16x32_bf16(a, b, c, 0, 0, 0);
}
__device__ __forceinline__ f32x16 mfma32(bf16x8 a, bf16x8 b, f32x16 c) {
  return __builtin_amdgcn_mfma_f32_32x32x16_bf16(a, b, c, 0, 0, 0);
}

#define SBAR() __builtin_amdgcn_s_barrier()

// ---------------- K0a: x f32 -> bf16 (8 elems/thread) -----------------------
__global__ void cvt_bf16(const float* __restrict__ src, u16* __restrict__ dst, int n8) {
  int i = blockIdx.x * blockDim.x + threadIdx.x;
  if (i >= n8) return;
  const float4* s = reinterpret_cast<const float4*>(src) + (size_t)i * 2;
  float4 a = s[0], b = s[1];
  union { u16 u[8]; uint4 v; } t;
  t.u[0] = f2bf(a.x); t.u[1] = f2bf(a.y); t.u[2] = f2bf(a.z); t.u[3] = f2bf(a.w);
  t.u[4] = f2bf(b.x); t.u[5] = f2bf(b.y); t.u[6] = f2bf(b.z); t.u[7] = f2bf(b.w);
  reinterpret_cast<uint4*>(dst)[i] = t.v;
}

// ---------------- K0b: all four weight matrices in one launch ---------------
__global__ void cvt_w(const float* __restrict__ Wq, const float* __restrict__ Wk,
                      const float* __restrict__ Wv, const float* __restrict__ Wo,
                      u16* __restrict__ wqkv, u16* __restrict__ wobf) {
  int idx = blockIdx.x * blockDim.x + threadIdx.x;   // 0 .. 131071
  int w = idx >> 15;                                  // 32768 uint4 per matrix
  int off = idx & 32767;
  const float* s = (w == 0) ? Wq : (w == 1) ? Wk : (w == 2) ? Wv : Wo;
  const float4* sp = reinterpret_cast<const float4*>(s) + (size_t)off * 2;
  float4 a = sp[0], b = sp[1];
  union { u16 u[8]; uint4 v; } t;
  t.u[0] = f2bf(a.x); t.u[1] = f2bf(a.y); t.u[2] = f2bf(a.z); t.u[3] = f2bf(a.w);
  t.u[4] = f2bf(b.x); t.u[5] = f2bf(b.y); t.u[6] = f2bf(b.z); t.u[7] = f2bf(b.w);
  if (w < 3) reinterpret_cast<uint4*>(wqkv)[w * 32768 + off] = t.v;
  else       reinterpret_cast<uint4*>(wobf)[off] = t.v;
}

// ---------------- shared GEMM pipeline macros (256x256, 32x32x16 MFMA) ------
#define GQ_READA(E, HH, MB)                                                 \
  _Pragma("unroll") for (int i = 0; i < 2; i++)                             \
  _Pragma("unroll") for (int q = 0; q < 2; q++)                             \
    af[i][q] = ld8(ldsA + ((E) * 2 + (HH)) * 8192 +                         \
                   (wr * 128 + ((MB) + i) * 32 + l31) * 32 +                \
                   ((q * 2 + lhi) ^ xkey) * 8);

#define GQ_READB(E, HH)                                                     \
  _Pragma("unroll") for (int j = 0; j < 2; j++)                             \
  _Pragma("unroll") for (int q = 0; q < 2; q++)                             \
    bfv[j][q] = ld8(ldsB + ((E) * 2 + (HH)) * 8192 +                        \
                    (wc * 64 + j * 32 + l31) * 32 +                         \
                    ((q * 2 + lhi) ^ xkey) * 8);

#define GQ_MFMA(MB)                                                         \
  __builtin_amdgcn_s_setprio(1);                                            \
  _Pragma("unroll") for (int i = 0; i < 2; i++)                             \
  _Pragma("unroll") for (int j = 0; j < 2; j++)                             \
  _Pragma("unroll") for (int q = 0; q < 2; q++)                             \
    acc[(MB) + i][j] = mfma32(af[i][q], bfv[j][q], acc[(MB) + i][j]);       \
  __builtin_amdgcn_s_setprio(0);

#define GQ_KLOOP()                                                          \
  stageA(0, 0, 0); stageB(0, 0, 0);                                         \
  stageA(0, 1, 0); stageB(0, 1, 0);                                         \
  stageA(1, 0, 1); stageB(1, 0, 1);                                         \
  asm volatile("s_waitcnt vmcnt(8)" ::: "memory");                          \
  SBAR();                                                                   \
  _Pragma("unroll 2") for (int s = 0; s < 8; ++s) {                         \
    const int e = s & 1;                                                    \
    bf16x8 af[2][2], bfv[2][2];                                             \
    GQ_READA(e, 0, 0)                                                       \
    GQ_READB(e, 0)                                                          \
    if (s < 7) stageA(e ^ 1, 1, s + 1);                                     \
    SBAR();                                                                 \
    GQ_MFMA(0)                                                              \
    SBAR();                                                                 \
    GQ_READA(e, 0, 2)                                                       \
    if (s < 7) stageB(e ^ 1, 1, s + 1);                                     \
    if (s < 7) { asm volatile("s_waitcnt vmcnt(8)" ::: "memory"); }         \
    else       { asm volatile("s_waitcnt vmcnt(0)" ::: "memory"); }         \
    SBAR();                                                                 \
    GQ_MFMA(2)                                                              \
    SBAR();                                                                 \
    GQ_READA(e, 1, 0)                                                       \
    GQ_READB(e, 1)                                                          \
    if (s < 6) stageA(e, 0, s + 2);                                         \
    SBAR();                                                                 \
    GQ_MFMA(0)                                                              \
    SBAR();                                                                 \
    GQ_READA(e, 1, 2)                                                       \
    if (s < 6) stageB(e, 0, s + 2);                                         \
    if (s < 6)      { asm volatile("s_waitcnt vmcnt(8)" ::: "memory"); }    \
    else if (s == 6){ asm volatile("s_waitcnt vmcnt(4)" ::: "memory"); }    \
    SBAR();                                                                 \
    GQ_MFMA(2)                                                              \
    SBAR();                                                                 \
  }

// ---------------- K1: qkv = x_bf @ Wqkv^T + bias ----------------------------
__global__ __launch_bounds__(512, 2) void k1_qkv(
    const u16* __restrict__ xbf,    // [M][512]
    const u16* __restrict__ wqkv,   // [1536][512]
    const float* __restrict__ bq, const float* __restrict__ bk, const float* __restrict__ bv,
    u16* __restrict__ qkv)          // [M][1536]
{
  __shared__ u16 lds[65536];        // 128 KiB
  u16* ldsA = lds;
  u16* ldsB = lds + 32768;

  const int tid = threadIdx.x;
  const int lane = tid & 63, wid = tid >> 6;
  const int wr = wid >> 2, wc = wid & 3;          // 2 x 4 wave grid
  const int l31 = lane & 31, lhi = lane >> 5;
  const int xkey = (l31 >> 1) & 3;

  const int cpx = gridDim.x >> 3;
  const int logical = (blockIdx.x & 7) * cpx + (blockIdx.x >> 3);
  const int m0 = (logical / 6) * 256;
  const int n0 = (logical % 6) * 256;

  const u16* ga = xbf + (size_t)m0 * E_;
  const u16* gb = wqkv + (size_t)n0 * E_;

  const int r0 = tid >> 2;
  const int c0 = ((tid & 3) ^ ((tid >> 3) & 3)) * 8;   // pre-swizzled src chunk

  auto stageA = [&](int e, int h, int kt) {
    const int kc = kt * 64 + h * 32;
    u16* base = ldsA + (e * 2 + h) * 8192;
    gl_lds16(ga + (size_t)r0 * E_ + kc + c0, base + wid * 512);
    gl_lds16(ga + (size_t)(r0 + 128) * E_ + kc + c0, base + 4096 + wid * 512);
  };
  auto stageB = [&](int e, int h, int kt) {
    const int kc = kt * 64 + h * 32;
    u16* base = ldsB + (e * 2 + h) * 8192;
    gl_lds16(gb + (size_t)r0 * E_ + kc + c0, base + wid * 512);
    gl_lds16(gb + (size_t)(r0 + 128) * E_ + kc + c0, base + 4096 + wid * 512);
  };

  f32x16 acc[4][2];
#pragma unroll
  for (int i = 0; i < 4; i++)
#pragma unroll
    for (int j = 0; j < 2; j++)
#pragma unroll
      for (int r = 0; r < 16; r++) acc[i][j][r] = 0.f;

  GQ_KLOOP()

  // epilogue: + bias, store bf16 token-major (two 64B half-wave segments/row)
  float bias2[2];
#pragma unroll
  for (int j = 0; j < 2; j++) {
    const int fcol = n0 + wc * 64 + j * 32 + l31;
    bias2[j] = fcol < 512 ? bq[fcol] : (fcol < 1024 ? bk[fcol - 512] : bv[fcol - 1024]);
  }
  const int fbase = n0 + wc * 64 + l31;
#pragma unroll
  for (int mi = 0; mi < 4; mi++)
#pragma unroll
    for (int r = 0; r < 16; r++) {
      const size_t row = m0 + wr * 128 + mi * 32 + (r & 3) + 8 * (r >> 2) + 4 * lhi;
      u16* dst = qkv + row * NF + fbase;
      dst[0]  = f2bf(acc[mi][0][r] + bias2[0]);
      dst[32] = f2bf(acc[mi][1][r] + bias2[1]);
    }
}

// ---------------- K2: per-(b,p,h) causal attention over T=64, D=64 ----------
// Round-12: V-gather hoisted before QK^T (latency hides under QK+softmax);
// per-wave lgkmcnt instead of block __syncthreads (waves fully independent);
// compile-time skip of fully-masked QK^T frags (ni>mi) and zero-P PV frags
// (ks==1 && mi<2).
__global__ __launch_bounds__(256) void k2_attn(
    const u16* __restrict__ qkv,   // [nb*MCH][1536], token n = b*MCH + t*P_ + p
    u16* __restrict__ o)           // [nb*MCH][512]
{
  __shared__ u16 Pl[4][64 * 72];
  const int tid = threadIdx.x, lane = tid & 63, wid = tid >> 6;
  const int gw = blockIdx.x * 4 + wid;
  const int b = gw >> 11;
  const int g = gw & 2047;
  const int h = g & 7, p = g >> 3;
  const int g4 = lane >> 4;
  const size_t ts = (size_t)P_ * NF;
  const u16* qb = qkv + (size_t)b * MCH * NF + (size_t)p * NF + h * D_;
  const u16* kb = qb + 512;
  const u16* vb = qb + 1024;
  u16* ob = o + (size_t)b * MCH * E_;

  bf16x8 qf[4][2], kf[4][2];
#pragma unroll
  for (int i = 0; i < 4; i++)
#pragma unroll
    for (int ks = 0; ks < 2; ks++) {
      const int rr = i * 16 + (lane & 15);
      const int dc = ks * 32 + g4 * 8;
      qf[i][ks] = ld8(qb + (size_t)rr * ts + dc);
      kf[i][ks] = ld8(kb + (size_t)rr * ts + dc);
    }

  // hoisted V-gather: issued before QK^T, consumed in PV (T14 issue-early)
  bf16x8 vfr[2][4];
#pragma unroll
  for (int ks = 0; ks < 2; ks++)
#pragma unroll
    for (int ni = 0; ni < 4; ni++) {
      union { u16 u[8]; bf16x8 b; } tv;
#pragma unroll
      for (int j = 0; j < 8; j++) {
        const int s = ks * 32 + g4 * 8 + j;
        tv.u[j] = vb[(size_t)s * ts + ni * 16 + (lane & 15)];
      }
      vfr[ks][ni] = tv.b;
    }

  f32x4 S[4][4];
#pragma unroll
  for (int i = 0; i < 4; i++)
#pragma unroll
    for (int j = 0; j < 4; j++) { f32x4 z = {0.f, 0.f, 0.f, 0.f}; S[i][j] = z; }
#pragma unroll
  for (int ks = 0; ks < 2; ks++)
#pragma unroll
    for (int mi = 0; mi < 4; mi++)
#pragma unroll
      for (int ni = 0; ni < 4; ni++)
        if (ni <= mi)   // frags with ni>mi are fully causal-masked
          S[mi][ni] = mfma16(qf[mi][ks], kf[ni][ks], S[mi][ni]);

  u16* pw = &Pl[wid][0];
#pragma unroll
  for (int mi = 0; mi < 4; mi++)
#pragma unroll
    for (int r = 0; r < 4; r++) {
      const int t = mi * 16 + g4 * 4 + r;
      float v[4]; float mx = -1e30f;
#pragma unroll
      for (int ni = 0; ni < 4; ni++) {
        const int s = ni * 16 + (lane & 15);
        v[ni] = (s <= t) ? S[mi][ni][r] * 0.125f : -1e30f;
        mx = fmaxf(mx, v[ni]);
      }
      mx = fmaxf(mx, __shfl_xor(mx, 1));
      mx = fmaxf(mx, __shfl_xor(mx, 2));
      mx = fmaxf(mx, __shfl_xor(mx, 4));
      mx = fmaxf(mx, __shfl_xor(mx, 8));
      float sum = 0.f; float pv[4];
#pragma unroll
      for (int ni = 0; ni < 4; ni++) {
        const int s = ni * 16 + (lane & 15);
        pv[ni] = (s <= t) ? __expf(v[ni] - mx) : 0.f;
        sum += pv[ni];
      }
      sum += __shfl_xor(sum, 1);
      sum += __shfl_xor(sum, 2);
      sum += __shfl_xor(sum, 4);
      sum += __shfl_xor(sum, 8);
      const float inv = 1.0f / sum;
#pragma unroll
      for (int ni = 0; ni < 4; ni++) {
        const int s = ni * 16 + (lane & 15);
        pw[t * 72 + s] = f2bf(pv[ni] * inv);
      }
    }
  // P_lds is per-wave private: per-wave LDS drain, no block barrier needed
  asm volatile("s_waitcnt lgkmcnt(0)" ::: "memory");

  f32x4 O[4][4];
#pragma unroll
  for (int i = 0; i < 4; i++)
#pragma unroll
    for (int j = 0; j < 4; j++) { f32x4 z = {0.f, 0.f, 0.f, 0.f}; O[i][j] = z; }
#pragma unroll
  for (int ks = 0; ks < 2; ks++) {
    bf16x8 pa[4];
#pragma unroll
    for (int mi = 0; mi < 4; mi++)
      pa[mi] = ld8(pw + (mi * 16 + (lane & 15)) * 72 + ks * 32 + g4 * 8);
#pragma unroll
    for (int mi = 0; mi < 4; mi++)
#pragma unroll
      for (int ni = 0; ni < 4; ni++)
        if (!(ks == 1 && mi < 2))   // P==0 for s>=32 when t<32
          O[mi][ni] = mfma16(pa[mi], vfr[ks][ni], O[mi][ni]);
  }
#pragma unroll
  for (int mi = 0; mi < 4; mi++)
#pragma unroll
    for (int ni = 0; ni < 4; ni++)
#pragma unroll
      for (int r = 0; r < 4; r++) {
        const int t = mi * 16 + g4 * 4 + r;
        const int d = ni * 16 + (lane & 15);
        ob[((size_t)t * P_ + p) * E_ + h * D_ + d] = f2bf(O[mi][ni][r]);
      }
}

// ---------------- K3a: y = o @ Wo^T + bo + x  (bf16 out) --------------------
__global__ __launch_bounds__(512, 2) void k3_gemm(
    const u16* __restrict__ obf,   // [M][512]
    const u16* __restrict__ wo,    // [512][512]
    const float* __restrict__ bo,
    const float* __restrict__ x,   // [M][512] f32
    u16* __restrict__ yb)          // [M][512] bf16
{
  __shared__ u16 lds[65536];
  u16* ldsA = lds;
  u16* ldsB = lds + 32768;

  const int tid = threadIdx.x;
  const int lane = tid & 63, wid = tid >> 6;
  const int wr = wid >> 2, wc = wid & 3;
  const int l31 = lane & 31, lhi = lane >> 5;
  const int xkey = (l31 >> 1) & 3;

  const int cpx = gridDim.x >> 3;
  const int logical = (blockIdx.x & 7) * cpx + (blockIdx.x >> 3);
  const int m0 = (logical >> 1) * 256;
  const int n0 = (logical & 1) * 256;

  const u16* ga = obf + (size_t)m0 * E_;
  const u16* gb = wo + (size_t)n0 * E_;

  const int r0 = tid >> 2;
  const int c0 = ((tid & 3) ^ ((tid >> 3) & 3)) * 8;

  auto stageA = [&](int e, int h, int kt) {
    const int kc = kt * 64 + h * 32;
    u16* base = ldsA + (e * 2 + h) * 8192;
    gl_lds16(ga + (size_t)r0 * E_ + kc + c0, base + wid * 512);
    gl_lds16(ga + (size_t)(r0 + 128) * E_ + kc + c0, base + 4096 + wid * 512);
  };
  auto stageB = [&](int e, int h, int kt) {
    const int kc = kt * 64 + h * 32;
    u16* base = ldsB + (e * 2 + h) * 8192;
    gl_lds16(gb + (size_t)r0 * E_ + kc + c0, base + wid * 512);
    gl_lds16(gb + (size_t)(r0 + 128) * E_ + kc + c0, base + 4096 + wid * 512);
  };

  f32x16 acc[4][2];
#pragma unroll
  for (int i = 0; i < 4; i++)
#pragma unroll
    for (int j = 0; j < 2; j++)
#pragma unroll
      for (int r = 0; r < 16; r++) acc[i][j][r] = 0.f;

  GQ_KLOOP()

  // epilogue: + bo + x (f32), store bf16
  float bias2[2];
#pragma unroll
  for (int j = 0; j < 2; j++)
    bias2[j] = bo[n0 + wc * 64 + j * 32 + l31];
  const int fbase = n0 + wc * 64 + l31;
#pragma unroll
  for (int mi = 0; mi < 4; mi++)
#pragma unroll
    for (int r = 0; r < 16; r++) {
      const size_t row = m0 + wr * 128 + mi * 32 + (r & 3) + 8 * (r >> 2) + 4 * lhi;
      u16* dst = yb + row * E_ + fbase;
      const float* xr = x + row * E_ + fbase;
      dst[0]  = f2bf(acc[mi][0][r] + bias2[0] + xr[0]);
      dst[32] = f2bf(acc[mi][1][r] + bias2[1] + xr[32]);
    }
}

// ---------------- K3b: out = LN(y) -----------------------------------------
__global__ __launch_bounds__(256) void k3_ln(
    const u16* __restrict__ yb, const float* __restrict__ lng,
    const float* __restrict__ lnb, float* __restrict__ out)
{
  const int lane = threadIdx.x & 63;
  const size_t row = (size_t)blockIdx.x * 4 + (threadIdx.x >> 6);
  const int c = lane * 8;
  const uint4 d = *reinterpret_cast<const uint4*>(yb + row * E_ + c);
  const uint32_t* dw = reinterpret_cast<const uint32_t*>(&d);
  float f[8];
#pragma unroll
  for (int j = 0; j < 4; j++) {
    union { uint32_t u; float v; } lo, hi;
    lo.u = dw[j] << 16; hi.u = dw[j] & 0xffff0000u;
    f[2 * j] = lo.v; f[2 * j + 1] = hi.v;
  }
  float s = 0.f, q = 0.f;
#pragma unroll
  for (int j = 0; j < 8; j++) { s += f[j]; q += f[j] * f[j]; }
#pragma unroll
  for (int d2 = 1; d2 < 64; d2 <<= 1) { s += __shfl_xor(s, d2); q += __shfl_xor(q, d2); }
  const float mean = s * (1.0f / 512.0f);
  const float var = q * (1.0f / 512.0f) - mean * mean;
  const float rs = rsqrtf(var + 1e-5f);
  float o8[8];
#pragma unroll
  for (int j = 0; j < 8; j++)
    o8[j] = (f[j] - mean) * rs * lng[c + j] + lnb[c + j];
  float4* op = reinterpret_cast<float4*>(out + row * E_ + c);
  op[0] = make_float4(o8[0], o8[1], o8[2], o8[3]);
  op[1] = make_float4(o8[4], o8[5], o8[6], o8[7]);
}

extern "C" void kernel_launch(void* const* d_in, const int* in_sizes, int n_in,
                              void* d_out, int out_size, void* d_ws, size_t ws_size,
                              hipStream_t stream) {
  const float* x   = (const float*)d_in[0];
  const float* Wq  = (const float*)d_in[1];
  const float* bq  = (const float*)d_in[2];
  const float* Wk  = (const float*)d_in[3];
  const float* bk  = (const float*)d_in[4];
  const float* Wv  = (const float*)d_in[5];
  const float* bv  = (const float*)d_in[6];
  const float* Wo  = (const float*)d_in[7];
  const float* bo  = (const float*)d_in[8];
  const float* lng = (const float*)d_in[9];
  const float* lnb = (const float*)d_in[10];
  float* out = (float*)d_out;
  uint8_t* ws = (uint8_t*)d_ws;

  const size_t NEED_BIG = 270532608ULL;
  if (ws_size >= NEED_BIG) {
    u16* wqkv = (u16*)(ws);
    u16* wobf = (u16*)(ws + 1572864);
    u16* xbf  = (u16*)(ws + 2097152);         // 64 MiB ; obf aliases after k1
    u16* qkvc = (u16*)(ws + 69206016);        // 192 MiB ; yb aliases after k2
    u16* obf  = xbf;                           // xbf dead after k1
    u16* yb   = qkvc;                          // qkvc dead after k2

    cvt_w<<<512, 256, 0, stream>>>(Wq, Wk, Wv, Wo, wqkv, wobf);
    cvt_bf16<<<16384, 256, 0, stream>>>(x, xbf, B_ * MCH * E_ / 8);
    k1_qkv<<<1536, 512, 0, stream>>>(xbf, wqkv, bq, bk, bv, qkvc);   // 256m x 6n
    k2_attn<<<2048, 256, 0, stream>>>(qkvc, obf);
    k3_gemm<<<512, 512, 0, stream>>>(obf, wobf, bo, x, yb);          // 256m x 2n
    k3_ln<<<16384, 256, 0, stream>>>(yb, lng, lnb, out);
  } else {
    u16* xbf  = (u16*)(ws);                   // 16 MiB
    u16* qkvc = (u16*)(ws + 16777216);        // 48 MiB ; yb aliases after k2
    u16* obf  = (u16*)(ws + 67108864);        // 16 MiB
    u16* wqkv = (u16*)(ws + 83886080);
    u16* wobf = (u16*)(ws + 85458944);
    u16* yb   = qkvc;

    cvt_w<<<512, 256, 0, stream>>>(Wq, Wk, Wv, Wo, wqkv, wobf);
    for (int b = 0; b < B_; ++b) {
      const float* xb = x + (size_t)b * MCH * E_;
      cvt_bf16<<<4096, 256, 0, stream>>>(xb, xbf, MCH * E_ / 8);
      k1_qkv<<<384, 512, 0, stream>>>(xbf, wqkv, bq, bk, bv, qkvc);  // 64m x 6n
      k2_attn<<<512, 256, 0, stream>>>(qkvc, obf);
      k3_gemm<<<128, 512, 0, stream>>>(obf, wobf, bo, xb, yb);       // 64m x 2n
      k3_ln<<<4096, 256, 0, stream>>>(yb, lng, lnb, out + (size_t)b * MCH * E_);
    }
  }
}

// Round 13
// 357.706 us; speedup vs baseline: 1.0093x; 1.0093x over previous
//
#include <hip/hip_runtime.h>
#include <stdint.h>

#define B_ 4
#define T_ 64
#define P_ 256
#define E_ 512
#define H_ 8
#define D_ 64
#define NF 1536
#define MCH 16384   // tokens per b-chunk (T_*P_)

typedef unsigned short u16;
typedef __attribute__((ext_vector_type(8))) __bf16 bf16x8;
typedef __attribute__((ext_vector_type(4))) float f32x4;
typedef __attribute__((ext_vector_type(16))) float f32x16;

__device__ __forceinline__ u16 f2bf(float x) {
  union { float f; uint32_t u; } a; a.f = x;
  uint32_t u = a.u;
  uint32_t r = (u + 0x7FFFu + ((u >> 16) & 1u)) >> 16;
  return (u16)r;
}

__device__ __forceinline__ bf16x8 ld8(const u16* p) {
  union { uint4 u; bf16x8 b; } t;
  t.u = *reinterpret_cast<const uint4*>(p);
  return t.b;
}

typedef __attribute__((address_space(3))) void lds_void;
typedef __attribute__((address_space(1))) void g_void;
__device__ __forceinline__ void gl_lds16(const void* g, void* l) {
  __builtin_amdgcn_global_load_lds((g_void*)g, (lds_void*)l, 16, 0, 0);
}

__device__ __forceinline__ f32x4 mfma16(bf16x8 a, bf16x8 b, f32x4 c) {
  return __builtin_amdgcn_mfma_f32_16x16x32_bf16(a, b, c, 0, 0, 0);
}
__device__ __forceinline__ f32x16 mfma32(bf16x8 a, bf16x8 b, f32x16 c) {
  return __builtin_amdgcn_mfma_f32_32x32x16_bf16(a, b, c, 0, 0, 0);
}

#define SBAR() __builtin_amdgcn_s_barrier()

// ---------------- K0: x + all four weights, one launch ----------------------
// items 0..4194303: x (uint4 each = 8 f32 -> 8 bf16); 4194304..4325375: weights
__global__ void cvt_all(const float* __restrict__ x,
                        const float* __restrict__ Wq, const float* __restrict__ Wk,
                        const float* __restrict__ Wv, const float* __restrict__ Wo,
                        u16* __restrict__ xbf, u16* __restrict__ wqkv,
                        u16* __restrict__ wobf) {
  const int idx = blockIdx.x * blockDim.x + threadIdx.x;
  const float* s;
  uint4* d;
  if (idx < 4194304) {
    s = x + (size_t)idx * 8;
    d = reinterpret_cast<uint4*>(xbf) + idx;
  } else {
    const int k = idx - 4194304;
    const int w = k >> 15, off = k & 32767;
    s = ((w == 0) ? Wq : (w == 1) ? Wk : (w == 2) ? Wv : Wo) + (size_t)off * 8;
    d = (w < 3) ? reinterpret_cast<uint4*>(wqkv) + w * 32768 + off
                : reinterpret_cast<uint4*>(wobf) + off;
  }
  const float4* sp = reinterpret_cast<const float4*>(s);
  float4 a = sp[0], b = sp[1];
  union { u16 u[8]; uint4 v; } t;
  t.u[0] = f2bf(a.x); t.u[1] = f2bf(a.y); t.u[2] = f2bf(a.z); t.u[3] = f2bf(a.w);
  t.u[4] = f2bf(b.x); t.u[5] = f2bf(b.y); t.u[6] = f2bf(b.z); t.u[7] = f2bf(b.w);
  *d = t.v;
}

// fallback-path converters
__global__ void cvt_bf16(const float* __restrict__ src, u16* __restrict__ dst, int n8) {
  int i = blockIdx.x * blockDim.x + threadIdx.x;
  if (i >= n8) return;
  const float4* s = reinterpret_cast<const float4*>(src) + (size_t)i * 2;
  float4 a = s[0], b = s[1];
  union { u16 u[8]; uint4 v; } t;
  t.u[0] = f2bf(a.x); t.u[1] = f2bf(a.y); t.u[2] = f2bf(a.z); t.u[3] = f2bf(a.w);
  t.u[4] = f2bf(b.x); t.u[5] = f2bf(b.y); t.u[6] = f2bf(b.z); t.u[7] = f2bf(b.w);
  reinterpret_cast<uint4*>(dst)[i] = t.v;
}
__global__ void cvt_w(const float* __restrict__ Wq, const float* __restrict__ Wk,
                      const float* __restrict__ Wv, const float* __restrict__ Wo,
                      u16* __restrict__ wqkv, u16* __restrict__ wobf) {
  int idx = blockIdx.x * blockDim.x + threadIdx.x;
  int w = idx >> 15;
  int off = idx & 32767;
  const float* s = (w == 0) ? Wq : (w == 1) ? Wk : (w == 2) ? Wv : Wo;
  const float4* sp = reinterpret_cast<const float4*>(s) + (size_t)off * 2;
  float4 a = sp[0], b = sp[1];
  union { u16 u[8]; uint4 v; } t;
  t.u[0] = f2bf(a.x); t.u[1] = f2bf(a.y); t.u[2] = f2bf(a.z); t.u[3] = f2bf(a.w);
  t.u[4] = f2bf(b.x); t.u[5] = f2bf(b.y); t.u[6] = f2bf(b.z); t.u[7] = f2bf(b.w);
  if (w < 3) reinterpret_cast<uint4*>(wqkv)[w * 32768 + off] = t.v;
  else       reinterpret_cast<uint4*>(wobf)[off] = t.v;
}

// ---------------- shared GEMM pipeline (256x256, 32x32x16, merged phases) ---
// Round-13: 2 phases per K-step (was 4) -> 4 barriers/K-step (was 8).
// Per phase: 12 ds_read_b128 (A mi0-3 + B), both stage calls, one counted
// vmcnt, SBAR, 16 MFMA, SBAR. Ledger (SP = stageA+stageB = 4 loads): steady
// state 3 SPs outstanding -> vmcnt(8) retires exactly the SP the next phase
// reads; tail vmcnt(4) @ s==6-h1, vmcnt(0) @ s==7-h0.
#define GQ_READA4(E, HH)                                                    \
  _Pragma("unroll") for (int i = 0; i < 4; i++)                             \
  _Pragma("unroll") for (int q = 0; q < 2; q++)                             \
    af[i][q] = ld8(ldsA + ((E) * 2 + (HH)) * 8192 +                         \
                   (wr * 128 + i * 32 + l31) * 32 +                         \
                   ((q * 2 + lhi) ^ xkey) * 8);

#define GQ_READB(E, HH)                                                     \
  _Pragma("unroll") for (int j = 0; j < 2; j++)                             \
  _Pragma("unroll") for (int q = 0; q < 2; q++)                             \
    bfv[j][q] = ld8(ldsB + ((E) * 2 + (HH)) * 8192 +                        \
                    (wc * 64 + j * 32 + l31) * 32 +                         \
                    ((q * 2 + lhi) ^ xkey) * 8);

#define GQ_MFMA16()                                                         \
  __builtin_amdgcn_s_setprio(1);                                            \
  _Pragma("unroll") for (int i = 0; i < 4; i++)                             \
  _Pragma("unroll") for (int j = 0; j < 2; j++)                             \
  _Pragma("unroll") for (int q = 0; q < 2; q++)                             \
    acc[i][j] = mfma32(af[i][q], bfv[j][q], acc[i][j]);                     \
  __builtin_amdgcn_s_setprio(0);

#define GQ_KLOOP()                                                          \
  stageA(0, 0, 0); stageB(0, 0, 0);                                         \
  stageA(0, 1, 0); stageB(0, 1, 0);                                         \
  stageA(1, 0, 1); stageB(1, 0, 1);                                         \
  asm volatile("s_waitcnt vmcnt(8)" ::: "memory");                          \
  SBAR();                                                                   \
  _Pragma("unroll 2") for (int s = 0; s < 8; ++s) {                         \
    const int e = s & 1;                                                    \
    bf16x8 af[4][2], bfv[2][2];                                             \
    /* ---- phase h=0 ---- */                                               \
    GQ_READA4(e, 0)                                                         \
    GQ_READB(e, 0)                                                          \
    if (s < 7) { stageA(e ^ 1, 1, s + 1); stageB(e ^ 1, 1, s + 1);          \
                 asm volatile("s_waitcnt vmcnt(8)" ::: "memory"); }         \
    else       { asm volatile("s_waitcnt vmcnt(0)" ::: "memory"); }         \
    SBAR();                                                                 \
    GQ_MFMA16()                                                             \
    SBAR();                                                                 \
    /* ---- phase h=1 ---- */                                               \
    GQ_READA4(e, 1)                                                         \
    GQ_READB(e, 1)                                                          \
    if (s < 6)      { stageA(e, 0, s + 2); stageB(e, 0, s + 2);             \
                      asm volatile("s_waitcnt vmcnt(8)" ::: "memory"); }    \
    else if (s == 6){ asm volatile("s_waitcnt vmcnt(4)" ::: "memory"); }    \
    SBAR();                                                                 \
    GQ_MFMA16()                                                             \
    SBAR();                                                                 \
  }

// ---------------- K1: qkv = x_bf @ Wqkv^T + bias ----------------------------
__global__ __launch_bounds__(512, 2) void k1_qkv(
    const u16* __restrict__ xbf,    // [M][512]
    const u16* __restrict__ wqkv,   // [1536][512]
    const float* __restrict__ bq, const float* __restrict__ bk, const float* __restrict__ bv,
    u16* __restrict__ qkv)          // [M][1536]
{
  __shared__ u16 lds[65536];        // 128 KiB
  u16* ldsA = lds;
  u16* ldsB = lds + 32768;

  const int tid = threadIdx.x;
  const int lane = tid & 63, wid = tid >> 6;
  const int wr = wid >> 2, wc = wid & 3;          // 2 x 4 wave grid
  const int l31 = lane & 31, lhi = lane >> 5;
  const int xkey = (l31 >> 1) & 3;

  const int cpx = gridDim.x >> 3;
  const int logical = (blockIdx.x & 7) * cpx + (blockIdx.x >> 3);
  const int m0 = (logical / 6) * 256;
  const int n0 = (logical % 6) * 256;

  const u16* ga = xbf + (size_t)m0 * E_;
  const u16* gb = wqkv + (size_t)n0 * E_;

  const int r0 = tid >> 2;
  const int c0 = ((tid & 3) ^ ((tid >> 3) & 3)) * 8;   // pre-swizzled src chunk

  auto stageA = [&](int e, int h, int kt) {
    const int kc = kt * 64 + h * 32;
    u16* base = ldsA + (e * 2 + h) * 8192;
    gl_lds16(ga + (size_t)r0 * E_ + kc + c0, base + wid * 512);
    gl_lds16(ga + (size_t)(r0 + 128) * E_ + kc + c0, base + 4096 + wid * 512);
  };
  auto stageB = [&](int e, int h, int kt) {
    const int kc = kt * 64 + h * 32;
    u16* base = ldsB + (e * 2 + h) * 8192;
    gl_lds16(gb + (size_t)r0 * E_ + kc + c0, base + wid * 512);
    gl_lds16(gb + (size_t)(r0 + 128) * E_ + kc + c0, base + 4096 + wid * 512);
  };

  f32x16 acc[4][2];
#pragma unroll
  for (int i = 0; i < 4; i++)
#pragma unroll
    for (int j = 0; j < 2; j++)
#pragma unroll
      for (int r = 0; r < 16; r++) acc[i][j][r] = 0.f;

  GQ_KLOOP()

  // epilogue: + bias, store bf16 token-major (two 64B half-wave segments/row)
  float bias2[2];
#pragma unroll
  for (int j = 0; j < 2; j++) {
    const int fcol = n0 + wc * 64 + j * 32 + l31;
    bias2[j] = fcol < 512 ? bq[fcol] : (fcol < 1024 ? bk[fcol - 512] : bv[fcol - 1024]);
  }
  const int fbase = n0 + wc * 64 + l31;
#pragma unroll
  for (int mi = 0; mi < 4; mi++)
#pragma unroll
    for (int r = 0; r < 16; r++) {
      const size_t row = m0 + wr * 128 + mi * 32 + (r & 3) + 8 * (r >> 2) + 4 * lhi;
      u16* dst = qkv + row * NF + fbase;
      dst[0]  = f2bf(acc[mi][0][r] + bias2[0]);
      dst[32] = f2bf(acc[mi][1][r] + bias2[1]);
    }
}

// ---------------- K2: per-(b,p,h) causal attention over T=64, D=64 ----------
__global__ __launch_bounds__(256) void k2_attn(
    const u16* __restrict__ qkv,   // [nb*MCH][1536], token n = b*MCH + t*P_ + p
    u16* __restrict__ o)           // [nb*MCH][512]
{
  __shared__ u16 Pl[4][64 * 72];
  const int tid = threadIdx.x, lane = tid & 63, wid = tid >> 6;
  const int gw = blockIdx.x * 4 + wid;
  const int b = gw >> 11;
  const int g = gw & 2047;
  const int h = g & 7, p = g >> 3;
  const int g4 = lane >> 4;
  const size_t ts = (size_t)P_ * NF;
  const u16* qb = qkv + (size_t)b * MCH * NF + (size_t)p * NF + h * D_;
  const u16* kb = qb + 512;
  const u16* vb = qb + 1024;
  u16* ob = o + (size_t)b * MCH * E_;

  bf16x8 qf[4][2], kf[4][2];
#pragma unroll
  for (int i = 0; i < 4; i++)
#pragma unroll
    for (int ks = 0; ks < 2; ks++) {
      const int rr = i * 16 + (lane & 15);
      const int dc = ks * 32 + g4 * 8;
      qf[i][ks] = ld8(qb + (size_t)rr * ts + dc);
      kf[i][ks] = ld8(kb + (size_t)rr * ts + dc);
    }

  // hoisted V-gather (T14 issue-early): flies under QK^T + softmax
  bf16x8 vfr[2][4];
#pragma unroll
  for (int ks = 0; ks < 2; ks++)
#pragma unroll
    for (int ni = 0; ni < 4; ni++) {
      union { u16 u[8]; bf16x8 b; } tv;
#pragma unroll
      for (int j = 0; j < 8; j++) {
        const int s = ks * 32 + g4 * 8 + j;
        tv.u[j] = vb[(size_t)s * ts + ni * 16 + (lane & 15)];
      }
      vfr[ks][ni] = tv.b;
    }

  f32x4 S[4][4];
#pragma unroll
  for (int i = 0; i < 4; i++)
#pragma unroll
    for (int j = 0; j < 4; j++) { f32x4 z = {0.f, 0.f, 0.f, 0.f}; S[i][j] = z; }
#pragma unroll
  for (int ks = 0; ks < 2; ks++)
#pragma unroll
    for (int mi = 0; mi < 4; mi++)
#pragma unroll
      for (int ni = 0; ni < 4; ni++)
        if (ni <= mi)   // frags with ni>mi are fully causal-masked
          S[mi][ni] = mfma16(qf[mi][ks], kf[ni][ks], S[mi][ni]);

  u16* pw = &Pl[wid][0];
#pragma unroll
  for (int mi = 0; mi < 4; mi++)
#pragma unroll
    for (int r = 0; r < 4; r++) {
      const int t = mi * 16 + g4 * 4 + r;
      float v[4]; float mx = -1e30f;
#pragma unroll
      for (int ni = 0; ni < 4; ni++) {
        const int s = ni * 16 + (lane & 15);
        v[ni] = (s <= t) ? S[mi][ni][r] * 0.125f : -1e30f;
        mx = fmaxf(mx, v[ni]);
      }
      mx = fmaxf(mx, __shfl_xor(mx, 1));
      mx = fmaxf(mx, __shfl_xor(mx, 2));
      mx = fmaxf(mx, __shfl_xor(mx, 4));
      mx = fmaxf(mx, __shfl_xor(mx, 8));
      float sum = 0.f; float pv[4];
#pragma unroll
      for (int ni = 0; ni < 4; ni++) {
        const int s = ni * 16 + (lane & 15);
        pv[ni] = (s <= t) ? __expf(v[ni] - mx) : 0.f;
        sum += pv[ni];
      }
      sum += __shfl_xor(sum, 1);
      sum += __shfl_xor(sum, 2);
      sum += __shfl_xor(sum, 4);
      sum += __shfl_xor(sum, 8);
      const float inv = 1.0f / sum;
#pragma unroll
      for (int ni = 0; ni < 4; ni++) {
        const int s = ni * 16 + (lane & 15);
        pw[t * 72 + s] = f2bf(pv[ni] * inv);
      }
    }
  // P_lds is per-wave private: per-wave LDS drain, no block barrier needed
  asm volatile("s_waitcnt lgkmcnt(0)" ::: "memory");

  f32x4 O[4][4];
#pragma unroll
  for (int i = 0; i < 4; i++)
#pragma unroll
    for (int j = 0; j < 4; j++) { f32x4 z = {0.f, 0.f, 0.f, 0.f}; O[i][j] = z; }
#pragma unroll
  for (int ks = 0; ks < 2; ks++) {
    bf16x8 pa[4];
#pragma unroll
    for (int mi = 0; mi < 4; mi++)
      pa[mi] = ld8(pw + (mi * 16 + (lane & 15)) * 72 + ks * 32 + g4 * 8);
#pragma unroll
    for (int mi = 0; mi < 4; mi++)
#pragma unroll
      for (int ni = 0; ni < 4; ni++)
        if (!(ks == 1 && mi < 2))   // P==0 for s>=32 when t<32
          O[mi][ni] = mfma16(pa[mi], vfr[ks][ni], O[mi][ni]);
  }
#pragma unroll
  for (int mi = 0; mi < 4; mi++)
#pragma unroll
    for (int ni = 0; ni < 4; ni++)
#pragma unroll
      for (int r = 0; r < 4; r++) {
        const int t = mi * 16 + g4 * 4 + r;
        const int d = ni * 16 + (lane & 15);
        ob[((size_t)t * P_ + p) * E_ + h * D_ + d] = f2bf(O[mi][ni][r]);
      }
}

// ---------------- K3a: y = o @ Wo^T + bo + x  (bf16 out) --------------------
__global__ __launch_bounds__(512, 2) void k3_gemm(
    const u16* __restrict__ obf,   // [M][512]
    const u16* __restrict__ wo,    // [512][512]
    const float* __restrict__ bo,
    const float* __restrict__ x,   // [M][512] f32
    u16* __restrict__ yb)          // [M][512] bf16
{
  __shared__ u16 lds[65536];
  u16* ldsA = lds;
  u16* ldsB = lds + 32768;

  const int tid = threadIdx.x;
  const int lane = tid & 63, wid = tid >> 6;
  const int wr = wid >> 2, wc = wid & 3;
  const int l31 = lane & 31, lhi = lane >> 5;
  const int xkey = (l31 >> 1) & 3;

  const int cpx = gridDim.x >> 3;
  const int logical = (blockIdx.x & 7) * cpx + (blockIdx.x >> 3);
  const int m0 = (logical >> 1) * 256;
  const int n0 = (logical & 1) * 256;

  const u16* ga = obf + (size_t)m0 * E_;
  const u16* gb = wo + (size_t)n0 * E_;

  const int r0 = tid >> 2;
  const int c0 = ((tid & 3) ^ ((tid >> 3) & 3)) * 8;

  auto stageA = [&](int e, int h, int kt) {
    const int kc = kt * 64 + h * 32;
    u16* base = ldsA + (e * 2 + h) * 8192;
    gl_lds16(ga + (size_t)r0 * E_ + kc + c0, base + wid * 512);
    gl_lds16(ga + (size_t)(r0 + 128) * E_ + kc + c0, base + 4096 + wid * 512);
  };
  auto stageB = [&](int e, int h, int kt) {
    const int kc = kt * 64 + h * 32;
    u16* base = ldsB + (e * 2 + h) * 8192;
    gl_lds16(gb + (size_t)r0 * E_ + kc + c0, base + wid * 512);
    gl_lds16(gb + (size_t)(r0 + 128) * E_ + kc + c0, base + 4096 + wid * 512);
  };

  f32x16 acc[4][2];
#pragma unroll
  for (int i = 0; i < 4; i++)
#pragma unroll
    for (int j = 0; j < 2; j++)
#pragma unroll
      for (int r = 0; r < 16; r++) acc[i][j][r] = 0.f;

  GQ_KLOOP()

  // epilogue: + bo + x (f32), store bf16
  float bias2[2];
#pragma unroll
  for (int j = 0; j < 2; j++)
    bias2[j] = bo[n0 + wc * 64 + j * 32 + l31];
  const int fbase = n0 + wc * 64 + l31;
#pragma unroll
  for (int mi = 0; mi < 4; mi++)
#pragma unroll
    for (int r = 0; r < 16; r++) {
      const size_t row = m0 + wr * 128 + mi * 32 + (r & 3) + 8 * (r >> 2) + 4 * lhi;
      u16* dst = yb + row * E_ + fbase;
      const float* xr = x + row * E_ + fbase;
      dst[0]  = f2bf(acc[mi][0][r] + bias2[0] + xr[0]);
      dst[32] = f2bf(acc[mi][1][r] + bias2[1] + xr[32]);
    }
}

// ---------------- K3b: out = LN(y) -----------------------------------------
__global__ __launch_bounds__(256) void k3_ln(
    const u16* __restrict__ yb, const float* __restrict__ lng,
    const float* __restrict__ lnb, float* __restrict__ out)
{
  const int lane = threadIdx.x & 63;
  const size_t row = (size_t)blockIdx.x * 4 + (threadIdx.x >> 6);
  const int c = lane * 8;
  const uint4 d = *reinterpret_cast<const uint4*>(yb + row * E_ + c);
  const uint32_t* dw = reinterpret_cast<const uint32_t*>(&d);
  float f[8];
#pragma unroll
  for (int j = 0; j < 4; j++) {
    union { uint32_t u; float v; } lo, hi;
    lo.u = dw[j] << 16; hi.u = dw[j] & 0xffff0000u;
    f[2 * j] = lo.v; f[2 * j + 1] = hi.v;
  }
  float s = 0.f, q = 0.f;
#pragma unroll
  for (int j = 0; j < 8; j++) { s += f[j]; q += f[j] * f[j]; }
#pragma unroll
  for (int d2 = 1; d2 < 64; d2 <<= 1) { s += __shfl_xor(s, d2); q += __shfl_xor(q, d2); }
  const float mean = s * (1.0f / 512.0f);
  const float var = q * (1.0f / 512.0f) - mean * mean;
  const float rs = rsqrtf(var + 1e-5f);
  float o8[8];
#pragma unroll
  for (int j = 0; j < 8; j++)
    o8[j] = (f[j] - mean) * rs * lng[c + j] + lnb[c + j];
  float4* op = reinterpret_cast<float4*>(out + row * E_ + c);
  op[0] = make_float4(o8[0], o8[1], o8[2], o8[3]);
  op[1] = make_float4(o8[4], o8[5], o8[6], o8[7]);
}

extern "C" void kernel_launch(void* const* d_in, const int* in_sizes, int n_in,
                              void* d_out, int out_size, void* d_ws, size_t ws_size,
                              hipStream_t stream) {
  const float* x   = (const float*)d_in[0];
  const float* Wq  = (const float*)d_in[1];
  const float* bq  = (const float*)d_in[2];
  const float* Wk  = (const float*)d_in[3];
  const float* bk  = (const float*)d_in[4];
  const float* Wv  = (const float*)d_in[5];
  const float* bv  = (const float*)d_in[6];
  const float* Wo  = (const float*)d_in[7];
  const float* bo  = (const float*)d_in[8];
  const float* lng = (const float*)d_in[9];
  const float* lnb = (const float*)d_in[10];
  float* out = (float*)d_out;
  uint8_t* ws = (uint8_t*)d_ws;

  const size_t NEED_BIG = 270532608ULL;
  if (ws_size >= NEED_BIG) {
    u16* wqkv = (u16*)(ws);
    u16* wobf = (u16*)(ws + 1572864);
    u16* xbf  = (u16*)(ws + 2097152);         // 64 MiB ; obf aliases after k1
    u16* qkvc = (u16*)(ws + 69206016);        // 192 MiB ; yb aliases after k2
    u16* obf  = xbf;                           // xbf dead after k1
    u16* yb   = qkvc;                          // qkvc dead after k2

    cvt_all<<<16896, 256, 0, stream>>>(x, Wq, Wk, Wv, Wo, xbf, wqkv, wobf);
    k1_qkv<<<1536, 512, 0, stream>>>(xbf, wqkv, bq, bk, bv, qkvc);   // 256m x 6n
    k2_attn<<<2048, 256, 0, stream>>>(qkvc, obf);
    k3_gemm<<<512, 512, 0, stream>>>(obf, wobf, bo, x, yb);          // 256m x 2n
    k3_ln<<<16384, 256, 0, stream>>>(yb, lng, lnb, out);
  } else {
    u16* xbf  = (u16*)(ws);                   // 16 MiB
    u16* qkvc = (u16*)(ws + 16777216);        // 48 MiB ; yb aliases after k2
    u16* obf  = (u16*)(ws + 67108864);        // 16 MiB
    u16* wqkv = (u16*)(ws + 83886080);
    u16* wobf = (u16*)(ws + 85458944);
    u16* yb   = qkvc;

    cvt_w<<<512, 256, 0, stream>>>(Wq, Wk, Wv, Wo, wqkv, wobf);
    for (int b = 0; b < B_; ++b) {
      const float* xb = x + (size_t)b * MCH * E_;
      cvt_bf16<<<4096, 256, 0, stream>>>(xb, xbf, MCH * E_ / 8);
      k1_qkv<<<384, 512, 0, stream>>>(xbf, wqkv, bq, bk, bv, qkvc);  // 64m x 6n
      k2_attn<<<512, 256, 0, stream>>>(qkvc, obf);
      k3_gemm<<<128, 512, 0, stream>>>(obf, wobf, bo, xb, yb);       // 64m x 2n
      k3_ln<<<4096, 256, 0, stream>>>(yb, lng, lnb, out + (size_t)b * MCH * E_);
    }
  }
}